// Round 1
// baseline (260.854 us; speedup 1.0000x reference)
//
#include <hip/hip_runtime.h>

// SpikingReadoutLayer: h2 = inputs @ W  -> linear scan over T
//   flt_t = a*flt_{t-1} + h_t ; out_t = b*out_{t-1} + flt_{t-1}
// out_rec[b,0,:]=0, out_rec[b,t+1,:]=out_t
constexpr int B = 128, T = 2000, H = 256, O = 16;
constexpr int TOUT = T + 1;           // 2001
constexpr float ALPHA = 0.95f, BETA = 0.9f;

// Kernel 1: h2[b,t,o] = sum_h in[b,t,h] * W[h,o], written in-place into
// d_out at [b, t, o] (t = 0..T-1). W staged in LDS ([h][o] layout, 16 KB);
// W reads are wave-uniform -> LDS broadcast, conflict-free.
// 256 threads/block, 2 t-rows per thread, 4 tiles of 512 t per batch.
__global__ __launch_bounds__(256) void h2_kernel(const float* __restrict__ in,
                                                 const float* __restrict__ W,
                                                 float* __restrict__ out) {
    __shared__ float Wl[H * O];       // 16 KB
    const int tid = threadIdx.x;
#pragma unroll
    for (int i = 0; i < (H * O) / 256; ++i)
        Wl[i * 256 + tid] = W[i * 256 + tid];
    __syncthreads();

    const int b    = blockIdx.x >> 2;
    const int tile = blockIdx.x & 3;
    const int t0   = tile * 512 + tid;       // always < 2000 (max 1791)
    const int t1   = t0 + 256;               // may be >= 2000 in last tile
    const bool vB  = (t1 < T);
    const float* rowA = in + ((size_t)b * T + t0) * H;
    const float* rowB = in + ((size_t)b * T + (vB ? t1 : t0)) * H; // clamp: no OOB

    float a0[O], a1[O];
#pragma unroll
    for (int o = 0; o < O; ++o) { a0[o] = 0.f; a1[o] = 0.f; }

    for (int h = 0; h < H; h += 4) {
        const float4 xA = *(const float4*)(rowA + h);
        const float4 xB = *(const float4*)(rowB + h);
        const float xa[4] = {xA.x, xA.y, xA.z, xA.w};
        const float xb[4] = {xB.x, xB.y, xB.z, xB.w};
#pragma unroll
        for (int j = 0; j < 4; ++j) {
            const float4 w0 = *(const float4*)(&Wl[(h + j) * O + 0]);
            const float4 w1 = *(const float4*)(&Wl[(h + j) * O + 4]);
            const float4 w2 = *(const float4*)(&Wl[(h + j) * O + 8]);
            const float4 w3 = *(const float4*)(&Wl[(h + j) * O + 12]);
            const float xj = xa[j], yj = xb[j];
            a0[0]  = fmaf(xj, w0.x, a0[0]);  a0[1]  = fmaf(xj, w0.y, a0[1]);
            a0[2]  = fmaf(xj, w0.z, a0[2]);  a0[3]  = fmaf(xj, w0.w, a0[3]);
            a0[4]  = fmaf(xj, w1.x, a0[4]);  a0[5]  = fmaf(xj, w1.y, a0[5]);
            a0[6]  = fmaf(xj, w1.z, a0[6]);  a0[7]  = fmaf(xj, w1.w, a0[7]);
            a0[8]  = fmaf(xj, w2.x, a0[8]);  a0[9]  = fmaf(xj, w2.y, a0[9]);
            a0[10] = fmaf(xj, w2.z, a0[10]); a0[11] = fmaf(xj, w2.w, a0[11]);
            a0[12] = fmaf(xj, w3.x, a0[12]); a0[13] = fmaf(xj, w3.y, a0[13]);
            a0[14] = fmaf(xj, w3.z, a0[14]); a0[15] = fmaf(xj, w3.w, a0[15]);
            a1[0]  = fmaf(yj, w0.x, a1[0]);  a1[1]  = fmaf(yj, w0.y, a1[1]);
            a1[2]  = fmaf(yj, w0.z, a1[2]);  a1[3]  = fmaf(yj, w0.w, a1[3]);
            a1[4]  = fmaf(yj, w1.x, a1[4]);  a1[5]  = fmaf(yj, w1.y, a1[5]);
            a1[6]  = fmaf(yj, w1.z, a1[6]);  a1[7]  = fmaf(yj, w1.w, a1[7]);
            a1[8]  = fmaf(yj, w2.x, a1[8]);  a1[9]  = fmaf(yj, w2.y, a1[9]);
            a1[10] = fmaf(yj, w2.z, a1[10]); a1[11] = fmaf(yj, w2.w, a1[11]);
            a1[12] = fmaf(yj, w3.x, a1[12]); a1[13] = fmaf(yj, w3.y, a1[13]);
            a1[14] = fmaf(yj, w3.z, a1[14]); a1[15] = fmaf(yj, w3.w, a1[15]);
        }
    }

    float4* dA = (float4*)(out + ((size_t)b * TOUT + t0) * O);
    dA[0] = make_float4(a0[0],  a0[1],  a0[2],  a0[3]);
    dA[1] = make_float4(a0[4],  a0[5],  a0[6],  a0[7]);
    dA[2] = make_float4(a0[8],  a0[9],  a0[10], a0[11]);
    dA[3] = make_float4(a0[12], a0[13], a0[14], a0[15]);
    if (vB) {
        float4* dB = (float4*)(out + ((size_t)b * TOUT + t1) * O);
        dB[0] = make_float4(a1[0],  a1[1],  a1[2],  a1[3]);
        dB[1] = make_float4(a1[4],  a1[5],  a1[6],  a1[7]);
        dB[2] = make_float4(a1[8],  a1[9],  a1[10], a1[11]);
        dB[3] = make_float4(a1[12], a1[13], a1[14], a1[15]);
    }
}

// Kernel 2: in-place linear scan. One thread per (b,o) chain.
// In-place safety: within an iteration the load of h[t+1] precedes the store
// of out[t+1] (same thread, same address -> program order preserved).
__global__ __launch_bounds__(64) void scan_kernel(float* __restrict__ out) {
    const int tid = blockIdx.x * blockDim.x + threadIdx.x;   // 0..2047
    const int b = tid >> 4, o = tid & 15;
    float* base = out + (size_t)b * TOUT * O + o;

    float flt = 0.f, oo = 0.f;
    float h = base[0];
    base[0] = 0.f;                       // out_rec[b,0,o] = 0
#pragma unroll 8
    for (int t = 0; t < T - 1; ++t) {
        const float hn = base[(size_t)(t + 1) * O];  // prefetch BEFORE store
        const float no = fmaf(BETA, oo, flt);        // uses OLD flt
        flt = fmaf(ALPHA, flt, h);
        base[(size_t)(t + 1) * O] = no;
        oo = no;
        h = hn;
    }
    // last step t = T-1: only the output store matters
    base[(size_t)T * O] = fmaf(BETA, oo, flt);
}

extern "C" void kernel_launch(void* const* d_in, const int* in_sizes, int n_in,
                              void* d_out, int out_size, void* d_ws, size_t ws_size,
                              hipStream_t stream) {
    const float* in = (const float*)d_in[0];   // [B, T, H]
    const float* W  = (const float*)d_in[1];   // [H, O]
    float* out = (float*)d_out;                // [B, T+1, O]

    h2_kernel<<<dim3(B * 4), dim3(256), 0, stream>>>(in, W, out);
    scan_kernel<<<dim3(32), dim3(64), 0, stream>>>(out);
}

// Round 2
// 213.089 us; speedup vs baseline: 1.2242x; 1.2242x over previous
//
#include <hip/hip_runtime.h>

// SpikingReadoutLayer:
//   h2[b,t,o] = sum_h in[b,t,h] * W[h,o]
//   flt_{t+1} = a*flt_t + h_t ; out_{t+1} = b*out_t + flt_t   (old flt)
//   out_rec[b,0,:]=0, out_rec[b,t+1,:]=out_{t+1}
//
// Strategy: linear-recurrence chunk decomposition. 25 chunks of 80 steps per
// (b,o) chain. Kernel 1 fuses matmul + chunk-local scan (zero initial state),
// writes local outputs to d_out and chunk-final states to d_ws. Kernel 2
// reconstructs each chunk's true start state from the closed form of A^k
// (A=[[a,0],[1,b]] => A^k=[[a^k,0],[g_k,b^k]], g_k=(a^k-b^k)/(a-b)) and adds
// the affine correction to every output element.

constexpr int B_ = 128, T_ = 2000, H_ = 256, O_ = 16;
constexpr int TOUT = T_ + 1;                 // 2001
constexpr int CHUNKS = 25, CL = 80;          // 25*80 = 2000
constexpr float ALPHA = 0.95f, BETA = 0.9f;
constexpr float INV_AB = 20.0f;              // 1/(ALPHA-BETA)
constexpr float L2A = -0.07400058144377693f; // log2(0.95)
constexpr float L2B = -0.15200309344504997f; // log2(0.90)

// Kernel 1: one wave per (b, chunk). lane = 16*c + o; group c covers h in
// [64c, 64c+64). W fragment (64 floats) lives in VGPRs. Per row: 16 broadcast
// float4 loads (coalescer dedups 4 distinct 16B segments per instr -> 64B,
// fully consumed), 64 FMAs (minimum), xor-16/32 butterfly => every lane holds
// h_t[o]. All lanes redundantly carry the (flt,out) state for their o, so the
// chunk-local scan is free; groups of 4 rows are stored with a full-wave
// 256B coalesced store (lane (c,o) stores row tg+c).
__global__ __launch_bounds__(256, 2)
void h2scan_kernel(const float* __restrict__ in, const float* __restrict__ W,
                   float* __restrict__ out, float* __restrict__ ws) {
    const int wid  = blockIdx.x * 4 + (threadIdx.x >> 6);   // 0..3199
    const int lane = threadIdx.x & 63;
    const int c = lane >> 4, o = lane & 15;
    const int b = wid / CHUNKS;
    const int j = wid - b * CHUNKS;

    // W fragment: wr[q] = W[c*64 + q][o]
    float wr[64];
    const float* Wp = W + (size_t)(c * 64) * O_ + o;
#pragma unroll
    for (int q = 0; q < 64; ++q) wr[q] = Wp[(size_t)q * O_];

    const float* ip = in + ((size_t)b * T_ + (size_t)j * CL) * H_ + c * 64;

    if (j == 0 && lane < 16) out[((size_t)b * TOUT) * O_ + o] = 0.f; // out_rec[b,0,o]

    float flt = 0.f, oo = 0.f;
    for (int tg = 0; tg < CL; tg += 4) {
        float sv[4];                                  // static-indexed (unrolled)
#pragma unroll
        for (int r = 0; r < 4; ++r) {
            const float* rp = ip + (size_t)(tg + r) * H_;
            float p0 = 0.f, p1 = 0.f, p2 = 0.f, p3 = 0.f;
#pragma unroll
            for (int q = 0; q < 16; ++q) {
                const float4 x = *(const float4*)(rp + 4 * q);
                p0 = fmaf(x.x, wr[4 * q + 0], p0);
                p1 = fmaf(x.y, wr[4 * q + 1], p1);
                p2 = fmaf(x.z, wr[4 * q + 2], p2);
                p3 = fmaf(x.w, wr[4 * q + 3], p3);
            }
            float h = (p0 + p1) + (p2 + p3);
            h += __shfl_xor(h, 16);
            h += __shfl_xor(h, 32);                   // all lanes: h_t for their o
            const float nout = fmaf(BETA, oo, flt);   // uses OLD flt
            flt = fmaf(ALPHA, flt, h);
            oo = nout;
            sv[r] = nout;
        }
        // full-wave coalesced store of 4 rows: lane (c,o) stores row tg+c
        const float mine = (c & 2) ? ((c & 1) ? sv[3] : sv[2])
                                   : ((c & 1) ? sv[1] : sv[0]);
        out[((size_t)b * TOUT + (size_t)j * CL + tg + 1 + c) * O_ + o] = mine;
    }
    if (lane < 16) {  // chunk-final local state (identical across c groups)
        float* wp = ws + ((size_t)(b * O_ + o) * CHUNKS + j) * 2;
        wp[0] = flt;
        wp[1] = oo;
    }
}

// Kernel 2: per (b, chunk j>0): start state s0 = sum_{m<j} A^{CL*(j-1-m)} * sigma_m
// (16 threads, one per o), then out[b, j*CL + tloc + 1, o] +=
//   g_{tloc+1} * f0 + beta^{tloc+1} * o0   for all 80*16 elements (coalesced RMW).
__global__ __launch_bounds__(256)
void fixup_kernel(float* __restrict__ out, const float* __restrict__ ws) {
    const int blk = blockIdx.x;              // 0..B*CHUNKS-1
    const int b = blk / CHUNKS;
    const int j = blk - b * CHUNKS;
    if (j == 0) return;                      // chunk 0: start state is exactly 0

    __shared__ float f0s[O_], o0s[O_];
    const int tid = threadIdx.x;
    if (tid < O_) {
        const float* wp = ws + ((size_t)(b * O_ + tid) * CHUNKS) * 2;
        float f = 0.f, oacc = 0.f;
        for (int m = 0; m < j; ++m) {
            const float k  = (float)((j - 1 - m) * CL);
            const float a  = exp2f(k * L2A);
            const float bb = exp2f(k * L2B);
            const float g  = (a - bb) * INV_AB;
            const float sf = wp[m * 2 + 0];
            const float so = wp[m * 2 + 1];
            f    = fmaf(a, sf, f);
            oacc = fmaf(g, sf, fmaf(bb, so, oacc));
        }
        f0s[tid] = f;
        o0s[tid] = oacc;
    }
    __syncthreads();

    const size_t rowbase = ((size_t)b * TOUT + (size_t)j * CL + 1) * O_;
    for (int e = tid; e < CL * O_; e += 256) {       // 1280 elems, 5 iters
        const int tloc = e >> 4;
        const int o = e & 15;
        const float k  = (float)(tloc + 1);
        const float a  = exp2f(k * L2A);
        const float bb = exp2f(k * L2B);
        const float g  = (a - bb) * INV_AB;
        out[rowbase + e] = fmaf(g, f0s[o], fmaf(bb, o0s[o], out[rowbase + e]));
    }
}

extern "C" void kernel_launch(void* const* d_in, const int* in_sizes, int n_in,
                              void* d_out, int out_size, void* d_ws, size_t ws_size,
                              hipStream_t stream) {
    const float* in = (const float*)d_in[0];   // [B, T, H]
    const float* W  = (const float*)d_in[1];   // [H, O]
    float* out = (float*)d_out;                // [B, T+1, O]
    float* ws  = (float*)d_ws;                 // needs 128*16*25*2*4 = 400 KiB

    h2scan_kernel<<<dim3((B_ * CHUNKS) / 4), dim3(256), 0, stream>>>(in, (const float*)d_in[1], out, ws);
    fixup_kernel<<<dim3(B_ * CHUNKS), dim3(256), 0, stream>>>(out, ws);
}

// Round 3
// 99.431 us; speedup vs baseline: 2.6235x; 2.1431x over previous
//
#include <hip/hip_runtime.h>

// SpikingReadoutLayer:
//   h2[b,t,o] = sum_h in[b,t,h] * W[h,o]
//   flt' = a*flt + h_t ; out' = b*out + flt (OLD flt); out_rec[b,0,:]=0
//
// Kernel 1: one block per (b, chunk of 250 rows). Thread-per-row matmul
// (W staged in LDS, read wave-uniform -> broadcast, conflict-free), then
// block-local scan in padded LDS, coalesced writeback. Chunk-final states
// to ws. Kernel 2: closed-form affine fixup (A^k has analytic form).

constexpr int B_ = 128, T_ = 2000, H_ = 256, O_ = 16;
constexpr int TOUT = T_ + 1;                 // 2001
constexpr int CHUNKS = 8, CL = 250;          // 8*250 = 2000
constexpr float ALPHA = 0.95f, BETA = 0.9f;
constexpr float INV_AB = 20.0f;              // 1/(ALPHA-BETA)
constexpr float L2A = -0.07400058144377693f; // log2(0.95)
constexpr float L2B = -0.15200309344504997f; // log2(0.90)
constexpr int PAD = 20;                      // tile row stride (floats): 80 B, 16B-aligned

__global__ __launch_bounds__(256, 4)
void h2scan_kernel(const float* __restrict__ in, const float* __restrict__ W,
                   float* __restrict__ out, float* __restrict__ ws) {
    __shared__ float Wl[H_ * O_];    // 16 KB
    __shared__ float tile[CL * PAD]; // 20 KB
    const int tid = threadIdx.x;
    const int b = blockIdx.x >> 3;   // CHUNKS = 8
    const int j = blockIdx.x & 7;

#pragma unroll
    for (int i = 0; i < (H_ * O_) / 256; ++i)
        Wl[i * 256 + tid] = W[i * 256 + tid];
    __syncthreads();

    float acc[16];
#pragma unroll
    for (int o = 0; o < 16; ++o) acc[o] = 0.f;

    if (tid < CL) {
        const float4* rp =
            (const float4*)(in + ((size_t)b * T_ + (size_t)j * CL + tid) * H_);
#pragma unroll
        for (int h0 = 0; h0 < H_; h0 += 32) {
            float4 xb[8];
#pragma unroll
            for (int k = 0; k < 8; ++k) xb[k] = rp[h0 / 4 + k];  // 2 full lines
#pragma unroll
            for (int k = 0; k < 8; ++k) {
                const float xv[4] = {xb[k].x, xb[k].y, xb[k].z, xb[k].w};
#pragma unroll
                for (int q = 0; q < 4; ++q) {
                    const int h = h0 + 4 * k + q;          // wave-uniform
                    const float4 w0 = *(const float4*)&Wl[h * 16 + 0];
                    const float4 w1 = *(const float4*)&Wl[h * 16 + 4];
                    const float4 w2 = *(const float4*)&Wl[h * 16 + 8];
                    const float4 w3 = *(const float4*)&Wl[h * 16 + 12];
                    const float x = xv[q];
                    acc[0]  = fmaf(x, w0.x, acc[0]);  acc[1]  = fmaf(x, w0.y, acc[1]);
                    acc[2]  = fmaf(x, w0.z, acc[2]);  acc[3]  = fmaf(x, w0.w, acc[3]);
                    acc[4]  = fmaf(x, w1.x, acc[4]);  acc[5]  = fmaf(x, w1.y, acc[5]);
                    acc[6]  = fmaf(x, w1.z, acc[6]);  acc[7]  = fmaf(x, w1.w, acc[7]);
                    acc[8]  = fmaf(x, w2.x, acc[8]);  acc[9]  = fmaf(x, w2.y, acc[9]);
                    acc[10] = fmaf(x, w2.z, acc[10]); acc[11] = fmaf(x, w2.w, acc[11]);
                    acc[12] = fmaf(x, w3.x, acc[12]); acc[13] = fmaf(x, w3.y, acc[13]);
                    acc[14] = fmaf(x, w3.z, acc[14]); acc[15] = fmaf(x, w3.w, acc[15]);
                }
            }
        }
        float4* tp = (float4*)&tile[tid * PAD];
        tp[0] = make_float4(acc[0],  acc[1],  acc[2],  acc[3]);
        tp[1] = make_float4(acc[4],  acc[5],  acc[6],  acc[7]);
        tp[2] = make_float4(acc[8],  acc[9],  acc[10], acc[11]);
        tp[3] = make_float4(acc[12], acc[13], acc[14], acc[15]);
    }
    __syncthreads();

    if (tid < O_) {   // 16 serial chains, conflict-free columns (PAD=20)
        float flt = 0.f, oo = 0.f;
        float* col = &tile[tid];
#pragma unroll 5
        for (int t = 0; t < CL; ++t) {
            const float h = col[t * PAD];
            const float no = fmaf(BETA, oo, flt);  // uses OLD flt
            flt = fmaf(ALPHA, flt, h);
            col[t * PAD] = no;
            oo = no;
        }
        float* wp = ws + ((size_t)(b * O_ + tid) * CHUNKS + j) * 2;
        wp[0] = flt;
        wp[1] = oo;
        if (j == 0) out[(size_t)b * TOUT * O_ + tid] = 0.f;  // out_rec[b,0,o]
    }
    __syncthreads();

    const size_t obase = ((size_t)b * TOUT + (size_t)j * CL + 1) * O_;
    for (int e = tid; e < CL * O_; e += 256)        // coalesced writeback
        out[obase + e] = tile[(e >> 4) * PAD + (e & 15)];
}

// Kernel 2: chunk j>0 start state s0 = sum_{m<j} A^{CL*(j-1-m)} * sigma_m,
// A^k = [[a^k,0],[g_k,b^k]], g_k=(a^k-b^k)/(a-b); then
// out[b, j*CL+tloc+1, o] += g_{tloc+1}*f0 + b^{tloc+1}*o0.
__global__ __launch_bounds__(256)
void fixup_kernel(float* __restrict__ out, const float* __restrict__ ws) {
    const int blk = blockIdx.x;
    const int b = blk >> 3;
    const int j = blk & 7;
    if (j == 0) return;

    __shared__ float f0s[O_], o0s[O_];
    const int tid = threadIdx.x;
    if (tid < O_) {
        const float* wp = ws + ((size_t)(b * O_ + tid) * CHUNKS) * 2;
        float f = 0.f, oacc = 0.f;
        for (int m = 0; m < j; ++m) {      // <= 7 terms
            const float k  = (float)((j - 1 - m) * CL);
            const float a  = exp2f(k * L2A);
            const float bb = exp2f(k * L2B);
            const float g  = (a - bb) * INV_AB;
            const float sf = wp[m * 2 + 0];
            const float so = wp[m * 2 + 1];
            f    = fmaf(a, sf, f);
            oacc = fmaf(g, sf, fmaf(bb, so, oacc));
        }
        f0s[tid] = f;
        o0s[tid] = oacc;
    }
    __syncthreads();

    const size_t rowbase = ((size_t)b * TOUT + (size_t)j * CL + 1) * O_;
    for (int e = tid; e < CL * O_; e += 256) {
        const int tloc = e >> 4;
        const int o = e & 15;
        const float k  = (float)(tloc + 1);
        const float a  = exp2f(k * L2A);
        const float bb = exp2f(k * L2B);
        const float g  = (a - bb) * INV_AB;
        out[rowbase + e] = fmaf(g, f0s[o], fmaf(bb, o0s[o], out[rowbase + e]));
    }
}

extern "C" void kernel_launch(void* const* d_in, const int* in_sizes, int n_in,
                              void* d_out, int out_size, void* d_ws, size_t ws_size,
                              hipStream_t stream) {
    const float* in = (const float*)d_in[0];   // [B, T, H]
    const float* W  = (const float*)d_in[1];   // [H, O]
    float* out = (float*)d_out;                // [B, T+1, O]
    float* ws  = (float*)d_ws;                 // 128*16*8*2*4 B = 128 KiB

    h2scan_kernel<<<dim3(B_ * CHUNKS), dim3(256), 0, stream>>>(in, W, out, ws);
    fixup_kernel<<<dim3(B_ * CHUNKS), dim3(256), 0, stream>>>(out, ws);
}